// Round 3
// baseline (505.412 us; speedup 1.0000x reference)
//
#include <hip/hip_runtime.h>
#include <hip/hip_bf16.h>
#include <stdint.h>

#define NBAGS 10000
#define DD 128
#define HH 256
#define OO 64

typedef __attribute__((ext_vector_type(4))) float f32x4;
typedef __attribute__((ext_vector_type(4))) unsigned int u32x4;
typedef __attribute__((ext_vector_type(2))) unsigned int u32x2;

__device__ __forceinline__ unsigned short f2bf(float f) {
    union { float f; unsigned int u; } v; v.f = f;
    unsigned int u = v.u;
    unsigned int lsb = (u >> 16) & 1u;
    u += 0x7fffu + lsb;           // round-to-nearest-even
    return (unsigned short)(u >> 16);
}
__device__ __forceinline__ float bf2f(unsigned short h) {
    union { unsigned int u; float f; } v; v.u = ((unsigned int)h) << 16;
    return v.f;
}

// ---------------- zero the bag-sum accumulator ----------------
__global__ void k_zero(float* __restrict__ p, int n4) {
    int i = blockIdx.x * blockDim.x + threadIdx.x;
    if (i < n4) ((f32x4*)p)[i] = f32x4{0.f, 0.f, 0.f, 0.f};
}

// ---------------- bag offsets via binary search (ids sorted, int32) ----------------
__global__ void k_offsets(const int* __restrict__ ids, int n, int* __restrict__ off) {
    int b = blockIdx.x * blockDim.x + threadIdx.x;
    if (b > NBAGS) return;
    int lo = 0, hi = n;
    while (lo < hi) {
        int mid = (lo + hi) >> 1;
        if (ids[mid] < b) lo = mid + 1; else hi = mid;
    }
    off[b] = lo;   // first index with ids[idx] >= b ; off[NBAGS] = n
}

// ---------------- W1 [128][256] f32  ->  W1t [256][128] bf16 ----------------
__global__ void k_w1t(const float* __restrict__ W1, unsigned short* __restrict__ W1t) {
    int k = blockIdx.x;      // 128 blocks
    int nn = threadIdx.x;    // 256 threads
    W1t[nn * DD + k] = f2bf(W1[k * HH + nn]);
}

// ---------------- fused GEMM1 + relu + segment-sum ----------------
// grid = ceil(n/64) blocks, 512 threads (8 waves).
// LDS: A 16384 (bf16 swizzled) + H 33792 (bf16 [64][264]) + ids 256 = 50432 B
#define HSTRIDE 264
__global__ __launch_bounds__(512) void k_gemm1(
    const float* __restrict__ x, const int* __restrict__ ids,
    const unsigned short* __restrict__ W1t, const float* __restrict__ b1,
    float* __restrict__ sums, int n)
{
    extern __shared__ char smem[];
    char*           As    = smem;                          // [64][128] bf16, XOR-swizzled
    unsigned short* Hs    = (unsigned short*)(smem + 16384); // [64][HSTRIDE] bf16
    int*            ids_s = (int*)(smem + 16384 + 33792);  // [64]

    const int t  = threadIdx.x;
    const int m0 = blockIdx.x * 64;
    const int w  = t >> 6;        // wave 0..7
    const int l  = t & 63;        // lane
    const int lr = l & 15;
    const int lg = l >> 4;

    // bag ids of this tile's rows (-1 past end)
    if (t < 64) {
        int gr = m0 + t;
        ids_s[t] = (gr < n) ? ids[gr] : -1;
    }

    // ---- B fragments straight from global (W1t is 64KB, L2-hot) ----
    u32x4 bf[2][4];
#pragma unroll
    for (int ct = 0; ct < 2; ++ct) {
        int ncol = w * 32 + ct * 16 + lr;
#pragma unroll
        for (int kc = 0; kc < 4; ++kc)
            bf[ct][kc] = *(const u32x4*)(W1t + ncol * DD + kc * 32 + lg * 8);
    }

    // ---- stage x tile f32 -> bf16 swizzled LDS ----
#pragma unroll
    for (int i = 0; i < 4; ++i) {
        int q   = i * 512 + t;        // 2048 float4 loads total
        int row = q >> 5;
        int kq  = q & 31;             // float4 index within row (k = 4*kq)
        int gr  = m0 + row;
        f32x4 v = f32x4{0.f, 0.f, 0.f, 0.f};
        if (gr < n) v = ((const f32x4*)x)[gr * 32 + kq];
        u32x2 u;
        u.x = (unsigned int)f2bf(v.x) | ((unsigned int)f2bf(v.y) << 16);
        u.y = (unsigned int)f2bf(v.z) | ((unsigned int)f2bf(v.w) << 16);
        int off = (row * 256 + kq * 8) ^ ((row & 7) << 4);
        *(u32x2*)(As + off) = u;
    }
    __syncthreads();

    // ---- MFMA: each wave does rows 0..63 x cols [32w, 32w+32) ----
    f32x4 acc[4][2];
#pragma unroll
    for (int mt = 0; mt < 4; ++mt)
#pragma unroll
        for (int ct = 0; ct < 2; ++ct)
            acc[mt][ct] = f32x4{0.f, 0.f, 0.f, 0.f};

#pragma unroll
    for (int mt = 0; mt < 4; ++mt) {
        u32x4 af[4];
        int rloc = mt * 16 + lr;
#pragma unroll
        for (int kc = 0; kc < 4; ++kc) {
            int off = (rloc * 256 + kc * 64 + lg * 16) ^ ((rloc & 7) << 4);
            af[kc] = *(const u32x4*)(As + off);
        }
#pragma unroll
        for (int ct = 0; ct < 2; ++ct)
#pragma unroll
            for (int kc = 0; kc < 4; ++kc)
                asm volatile("v_mfma_f32_16x16x32_bf16 %0, %1, %2, %0"
                             : "+v"(acc[mt][ct])
                             : "v"(af[kc]), "v"(bf[ct][kc]));
    }
    asm volatile("s_nop 7\n\ts_nop 7" :::);   // MFMA->VALU read hazard guard

    // ---- bias + relu -> Hs (bf16, stride 264) ----
#pragma unroll
    for (int ct = 0; ct < 2; ++ct) {
        int col = w * 32 + ct * 16 + lr;
        float bias = b1[col];
#pragma unroll
        for (int mt = 0; mt < 4; ++mt) {
            int r0 = mt * 16 + lg * 4;
#pragma unroll
            for (int j = 0; j < 4; ++j) {
                float hv = acc[mt][ct][j] + bias;
                hv = hv > 0.f ? hv : 0.f;
                Hs[(r0 + j) * HSTRIDE + col] = f2bf(hv);
            }
        }
    }
    __syncthreads();

    // ---- segment-sum scan: thread t -> column c, half rh ----
    {
        int c  = t & 255;
        int rh = t >> 8;
        int rbeg = rh * 32, rend = rbeg + 32;
        float run = 0.f;
        int cur = -1;
        for (int r = rbeg; r < rend; ++r) {
            int b = ids_s[r];
            if (b != cur) {
                if (cur >= 0 && cur < NBAGS) atomicAdd(&sums[cur * HH + c], run);
                run = 0.f;
                cur = b;
            }
            run += bf2f(Hs[r * HSTRIDE + c]);
        }
        if (cur >= 0 && cur < NBAGS) atomicAdd(&sums[cur * HH + c], run);
    }
}

// ---------------- means @ W2 + b2 ----------------
__global__ __launch_bounds__(64) void k_out(
    const float* __restrict__ sums, const int* __restrict__ off,
    const float* __restrict__ W2, const float* __restrict__ b2,
    float* __restrict__ out)
{
    int b = blockIdx.x, t = threadIdx.x;
    int cnt = off[b + 1] - off[b];
    float inv = 1.0f / (float)(cnt > 0 ? cnt : 1);
    const float* s = sums + b * HH;
    float acc = 0.f;
#pragma unroll 4
    for (int k = 0; k < HH; ++k)
        acc += s[k] * W2[k * OO + t];
    out[b * OO + t] = acc * inv + b2[t];
}

extern "C" void kernel_launch(void* const* d_in, const int* in_sizes, int n_in,
                              void* d_out, int out_size, void* d_ws, size_t ws_size,
                              hipStream_t stream)
{
    const float* x   = (const float*)d_in[0];
    const int*   ids = (const int*)d_in[1];     // int64 in reference -> int32 on device
    const float* W1  = (const float*)d_in[2];
    const float* b1  = (const float*)d_in[3];
    const float* W2  = (const float*)d_in[4];
    const float* b2  = (const float*)d_in[5];
    float* out = (float*)d_out;
    const int n = in_sizes[1];           // 500000 instances

    char* ws = (char*)d_ws;
    float*          sums = (float*)ws;                         // 10,240,000 B
    int*            off  = (int*)(ws + 10240000);              // 40,004 B
    unsigned short* W1t  = (unsigned short*)(ws + 10280016);   // 65,536 B (16B aligned)

    k_zero<<<(NBAGS * HH / 4 + 255) / 256, 256, 0, stream>>>(sums, NBAGS * HH / 4);
    k_offsets<<<(NBAGS + 1 + 255) / 256, 256, 0, stream>>>(ids, n, off);
    k_w1t<<<DD, HH, 0, stream>>>(W1, W1t);

    int mtiles = (n + 63) / 64;
    k_gemm1<<<mtiles, 512, 50432, stream>>>(x, ids, W1t, b1, sums, n);

    k_out<<<NBAGS, OO, 0, stream>>>(sums, off, W2, b2, out);
}

// Round 5
// 410.636 us; speedup vs baseline: 1.2308x; 1.2308x over previous
//
#include <hip/hip_runtime.h>
#include <hip/hip_bf16.h>
#include <stdint.h>

#define NBAGS 10000
#define DD 128
#define HH 256
#define OO 64
#define HSTR 72          // u16 col stride for Hs (col-major); 144 B per col, 16B-aligned

typedef __attribute__((ext_vector_type(4))) float f32x4;
typedef __attribute__((ext_vector_type(4))) unsigned int u32x4;
typedef __attribute__((ext_vector_type(2))) unsigned int u32x2;

__device__ __forceinline__ unsigned short f2bf(float f) {
    union { float f; unsigned int u; } v; v.f = f;
    unsigned int u = v.u;
    unsigned int lsb = (u >> 16) & 1u;
    u += 0x7fffu + lsb;           // RNE
    return (unsigned short)(u >> 16);
}

// ---------------- prep: zero sums + bag offsets + W1 transpose->bf16 ----------------
// grid = 640 (zero) + 40 (offsets) + 128 (w1t) = 808 blocks x 256 threads
__global__ __launch_bounds__(256) void k_prep(
    const int* __restrict__ ids, int n, const float* __restrict__ W1,
    float* __restrict__ sums, int* __restrict__ off, unsigned short* __restrict__ W1t)
{
    int b = blockIdx.x, t = threadIdx.x;
    if (b < 640) {
        int i = b * 256 + t;
        if (i < NBAGS * HH / 4) ((f32x4*)sums)[i] = f32x4{0.f, 0.f, 0.f, 0.f};
    } else if (b < 680) {
        int g = (b - 640) * 256 + t;
        if (g <= NBAGS) {
            int lo = 0, hi = n;
            while (lo < hi) { int mid = (lo + hi) >> 1; if (ids[mid] < g) lo = mid + 1; else hi = mid; }
            off[g] = lo;          // first idx with ids[idx] >= g ; off[NBAGS] = n
        }
    } else {
        int k = b - 680;          // 0..127
        W1t[t * DD + k] = f2bf(W1[k * HH + t]);
    }
}

// ---------------- fused GEMM1 + relu + segment-sum (persistent, pipelined) ----------------
// grid = 512 blocks x 512 threads (8 waves), grid-stride over 64-row tiles.
// LDS: As 16384 (bf16 swizzled [64][128]) + Hs 36864 (u16 col-major [256][72]) + ids 256 = 53504 B
__global__ __launch_bounds__(512) void k_gemm1(
    const float* __restrict__ x, const int* __restrict__ ids,
    const unsigned short* __restrict__ W1t, const float* __restrict__ b1,
    float* __restrict__ sums, int n, int mtiles)
{
    extern __shared__ char smem[];
    char*           As    = smem;                              // 16384 B
    unsigned short* Hs    = (unsigned short*)(smem + 16384);   // 36864 B
    int*            ids_s = (int*)(smem + 16384 + 36864);      // 256 B

    const int t  = threadIdx.x;
    const int w  = t >> 6;        // wave 0..7
    const int l  = t & 63;
    const int lr = l & 15;
    const int lg = l >> 4;
    const int kq = t & 31;        // float4 column within a row
    const int rb = t >> 5;        // 0..15 staging base row

    // ---- B fragments + bias: loaded ONCE per block ----
    u32x4 bfr[2][4];
#pragma unroll
    for (int ct = 0; ct < 2; ++ct) {
        int ncol = w * 32 + ct * 16 + lr;
#pragma unroll
        for (int kc = 0; kc < 4; ++kc)
            bfr[ct][kc] = *(const u32x4*)(W1t + ncol * DD + kc * 32 + lg * 8);
    }
    const float bias0 = b1[w * 32 + lr];
    const float bias1 = b1[w * 32 + 16 + lr];

    // As write offsets for my 4 staged rows (XOR-swizzled)
    int aoff[4];
#pragma unroll
    for (int i = 0; i < 4; ++i) {
        int row = rb + i * 16;
        aoff[i] = (row * 256 + kq * 8) ^ ((row & 7) << 4);
    }

    const int G = gridDim.x;
    f32x4 xv[4];
    int myid = -1;

    int tile = blockIdx.x;
    {   // prologue: issue loads for first tile
        int m0 = tile << 6;
#pragma unroll
        for (int i = 0; i < 4; ++i) {
            int gr = m0 + rb + i * 16;
            xv[i] = (gr < n) ? ((const f32x4*)x)[gr * 32 + kq] : f32x4{0.f, 0.f, 0.f, 0.f};
        }
        if (t < 64) myid = (m0 + t < n) ? ids[m0 + t] : -1;
    }

    for (; tile < mtiles; tile += G) {
        // ---- C phase: staged regs -> As (bf16, swizzled) ----
#pragma unroll
        for (int i = 0; i < 4; ++i) {
            u32x2 u;
            asm("v_cvt_pk_bf16_f32 %0, %1, %2" : "=v"(u.x) : "v"(xv[i].x), "v"(xv[i].y));
            asm("v_cvt_pk_bf16_f32 %0, %1, %2" : "=v"(u.y) : "v"(xv[i].z), "v"(xv[i].w));
            *(u32x2*)(As + aoff[i]) = u;
        }
        int idreg = myid;
        __syncthreads();                       // B1: As ready, prev scan done
        if (t < 64) ids_s[t] = idreg;

        // ---- issue next tile's global loads (in flight across MFMA + scan) ----
        int nt = tile + G;
        if (nt < mtiles) {
            int m0 = nt << 6;
#pragma unroll
            for (int i = 0; i < 4; ++i) {
                int gr = m0 + rb + i * 16;
                xv[i] = (gr < n) ? ((const f32x4*)x)[gr * 32 + kq] : f32x4{0.f, 0.f, 0.f, 0.f};
            }
            if (t < 64) myid = (m0 + t < n) ? ids[m0 + t] : -1;
        }

        // ---- MFMA: rows 0..63 x cols [32w, 32w+32) ----
        f32x4 acc[4][2];
#pragma unroll
        for (int mt = 0; mt < 4; ++mt) {
            acc[mt][0] = f32x4{0.f, 0.f, 0.f, 0.f};
            acc[mt][1] = f32x4{0.f, 0.f, 0.f, 0.f};
        }
#pragma unroll
        for (int mt = 0; mt < 4; ++mt) {
            u32x4 af[4];
            int rloc = mt * 16 + lr;
            int sw = (rloc & 7) << 4;
#pragma unroll
            for (int kc = 0; kc < 4; ++kc)
                af[kc] = *(const u32x4*)(As + ((rloc * 256 + kc * 64 + lg * 16) ^ sw));
#pragma unroll
            for (int ct = 0; ct < 2; ++ct)
#pragma unroll
                for (int kc = 0; kc < 4; ++kc)
                    asm volatile("v_mfma_f32_16x16x32_bf16 %0, %1, %2, %0"
                                 : "+v"(acc[mt][ct]) : "v"(af[kc]), "v"(bfr[ct][kc]));
        }
        asm volatile("s_nop 7\n\ts_nop 7" :::);   // MFMA->VALU hazard guard

        // ---- bias + relu -> Hs col-major (4 rows packed per ds_write_b64) ----
#pragma unroll
        for (int ct = 0; ct < 2; ++ct) {
            int col = w * 32 + ct * 16 + lr;
            float bias = ct ? bias1 : bias0;
#pragma unroll
            for (int mt = 0; mt < 4; ++mt) {
                int r0 = mt * 16 + lg * 4;
                float h0 = fmaxf(acc[mt][ct][0] + bias, 0.f);
                float h1 = fmaxf(acc[mt][ct][1] + bias, 0.f);
                float h2 = fmaxf(acc[mt][ct][2] + bias, 0.f);
                float h3 = fmaxf(acc[mt][ct][3] + bias, 0.f);
                u32x2 u;
                asm("v_cvt_pk_bf16_f32 %0, %1, %2" : "=v"(u.x) : "v"(h0), "v"(h1));
                asm("v_cvt_pk_bf16_f32 %0, %1, %2" : "=v"(u.y) : "v"(h2), "v"(h3));
                *(u32x2*)((char*)Hs + col * (HSTR * 2) + r0 * 2) = u;
            }
        }
        __syncthreads();                       // B2: Hs + ids_s ready

        // ---- segment-sum scan: thread -> (column c, half rh), vectorized reads ----
        {
            int c  = t & 255;
            int rh = t >> 8;
            const char* base = (const char*)Hs + c * (HSTR * 2) + rh * 64;
            u32x4 hv[4];
#pragma unroll
            for (int i = 0; i < 4; ++i) hv[i] = *(const u32x4*)(base + i * 16);
            float run = 0.f;
            int cur = -1;
            int rbase = rh * 32;
#pragma unroll
            for (int i = 0; i < 4; ++i) {
#pragma unroll
                for (int q = 0; q < 4; ++q) {
                    int r = rbase + i * 8 + q * 2;
                    unsigned int wd = hv[i][q];
                    int b0 = ids_s[r], b2v = ids_s[r + 1];
                    if (b0 != cur) {
                        if (cur >= 0 && cur < NBAGS) atomicAdd(&sums[cur * HH + c], run);
                        run = 0.f; cur = b0;
                    }
                    run += __uint_as_float(wd << 16);
                    if (b2v != cur) {
                        if (cur >= 0 && cur < NBAGS) atomicAdd(&sums[cur * HH + c], run);
                        run = 0.f; cur = b2v;
                    }
                    run += __uint_as_float(wd & 0xffff0000u);
                }
            }
            if (cur >= 0 && cur < NBAGS) atomicAdd(&sums[cur * HH + c], run);
        }
    }
}

// ---------------- means @ W2 + b2 : 4 bags per block (one per wave) ----------------
__global__ __launch_bounds__(256) void k_out(
    const float* __restrict__ sums, const int* __restrict__ off,
    const float* __restrict__ W2, const float* __restrict__ b2,
    float* __restrict__ out)
{
    int wv = threadIdx.x >> 6, l = threadIdx.x & 63;
    int b = blockIdx.x * 4 + wv;
    if (b >= NBAGS) return;
    int cnt = off[b + 1] - off[b];
    float inv = 1.0f / (float)(cnt > 0 ? cnt : 1);
    const float* s = sums + b * HH;
    float acc0 = 0.f, acc1 = 0.f;
#pragma unroll 8
    for (int k = 0; k < HH; k += 2) {
        acc0 = fmaf(s[k],     W2[k * OO + l],       acc0);
        acc1 = fmaf(s[k + 1], W2[(k + 1) * OO + l], acc1);
    }
    out[b * OO + l] = (acc0 + acc1) * inv + b2[l];
}

extern "C" void kernel_launch(void* const* d_in, const int* in_sizes, int n_in,
                              void* d_out, int out_size, void* d_ws, size_t ws_size,
                              hipStream_t stream)
{
    const float* x   = (const float*)d_in[0];
    const int*   ids = (const int*)d_in[1];     // int64 in reference -> int32 on device
    const float* W1  = (const float*)d_in[2];
    const float* b1  = (const float*)d_in[3];
    const float* W2  = (const float*)d_in[4];
    const float* b2  = (const float*)d_in[5];
    float* out = (float*)d_out;
    const int n = in_sizes[1];                  // 500000 instances

    char* ws = (char*)d_ws;
    float*          sums = (float*)ws;                         // 10,240,000 B
    int*            off  = (int*)(ws + 10240000);              // 40,004 B
    unsigned short* W1t  = (unsigned short*)(ws + 10280016);   // 65,536 B (16B aligned)

    const int mtiles = (n + 63) >> 6;

    k_prep<<<808, 256, 0, stream>>>(ids, n, W1, sums, off, W1t);

    int grid = mtiles < 512 ? mtiles : 512;
    k_gemm1<<<grid, 512, 53504, stream>>>(x, ids, W1t, b1, sums, n, mtiles);

    k_out<<<(NBAGS + 3) / 4, 256, 0, stream>>>(sums, off, W2, b2, out);
}